// Round 1
// baseline (355.657 us; speedup 1.0000x reference)
//
#include <hip/hip_runtime.h>

// ConnectedWithinCutoff: B=64 graphs, n=512 nodes each, cutoff=5.0, no self loops.
// d_out (float32, flat concat):
//   [0, 2P)        edge_index_all  (pairs (src,dst) as floats)
//   [2P, 3P)       edge_mask       (1.0 / 0.0)
//   [3P, 3P+B)     num_edges       (per-graph float count)
//   [3P+B, 4P+B)   distances
// P = B*n*n. Write-BW bound: ~268 MB out -> ~45 us floor at 6 TB/s.

__global__ void zero_counts_kernel(float* __restrict__ ne, int B) {
    int t = blockIdx.x * blockDim.x + threadIdx.x;
    if (t < B) ne[t] = 0.0f;
}

__global__ __launch_bounds__(256) void cwc_kernel(
    const float* __restrict__ pos,
    float* __restrict__ ei,
    float* __restrict__ maskout,
    float* __restrict__ numedges,
    float* __restrict__ distout,
    int n, int tpr, int rows_per_block)
{
    extern __shared__ float spos[];  // n*3 floats (6 KB for n=512)

    const int rows0 = blockIdx.x * rows_per_block;
    const int b = rows0 / n;  // same graph for all rows in block (n even)
    const int nf = n * 3;

    // cooperative coalesced load of graph b's positions into LDS
    const float* gp = pos + (long long)b * nf;
    for (int idx = threadIdx.x; idx < nf; idx += blockDim.x)
        spos[idx] = gp[idx];
    __syncthreads();

    const int r = threadIdx.x / tpr;
    const int t = threadIdx.x - r * tpr;
    const int grow = rows0 + r;      // global row = b*n + i
    const int i = grow - b * n;

    const float px = spos[3 * i + 0];
    const float py = spos[3 * i + 1];
    const float pz = spos[3 * i + 2];

    const int j0 = t * 4;
    const int rowbase = grow * n;    // pair index of (b,i,0); fits int (<2^25)

    // 4 consecutive nodes = 12 contiguous floats, 16B-aligned (48*t bytes)
    float4 q0 = *(const float4*)(spos + 3 * j0);
    float4 q1 = *(const float4*)(spos + 3 * j0 + 4);
    float4 q2 = *(const float4*)(spos + 3 * j0 + 8);
    float qx[4] = {q0.x, q0.w, q1.z, q2.y};
    float qy[4] = {q0.y, q1.x, q1.w, q2.z};
    float qz[4] = {q0.z, q1.y, q2.x, q2.w};

    float d[4], m[4];
    int cnt = 0;
#pragma unroll
    for (int jj = 0; jj < 4; ++jj) {
        float dx = px - qx[jj];
        float dy = py - qy[jj];
        float dz = pz - qz[jj];
        float d2 = fmaf(dx, dx, fmaf(dy, dy, dz * dz));
        float dd = sqrtf(d2);
        d[jj] = dd;
        bool keep = (dd <= 5.0f) && ((j0 + jj) != i);
        m[jj] = keep ? 1.0f : 0.0f;
        cnt += keep ? 1 : 0;
    }

    *(float4*)(distout + rowbase + j0) = float4{d[0], d[1], d[2], d[3]};
    *(float4*)(maskout + rowbase + j0) = float4{m[0], m[1], m[2], m[3]};

    const float gif = (float)grow;              // src global index (<= 32767, exact in f32)
    const float gjf = (float)(b * n + j0);      // dst global index base
    float4* eip = (float4*)(ei + 2 * (long long)(rowbase + j0));
    eip[0] = float4{gif, gjf,        gif, gjf + 1.0f};
    eip[1] = float4{gif, gjf + 2.0f, gif, gjf + 3.0f};

    // block-level count reduction -> one atomic per block (G12)
#pragma unroll
    for (int off = 32; off > 0; off >>= 1)
        cnt += __shfl_down(cnt, off, 64);
    __shared__ int wsum[16];
    const int wave = threadIdx.x >> 6;
    const int lane = threadIdx.x & 63;
    if (lane == 0) wsum[wave] = cnt;
    __syncthreads();
    if (threadIdx.x == 0) {
        int nw = blockDim.x >> 6;
        int s = 0;
        for (int w = 0; w < nw; ++w) s += wsum[w];
        atomicAdd(numedges + b, (float)s);
    }
}

extern "C" void kernel_launch(void* const* d_in, const int* in_sizes, int n_in,
                              void* d_out, int out_size, void* d_ws, size_t ws_size,
                              hipStream_t stream) {
    const float* pos = (const float*)d_in[1];  // [B*n, 3] float32
    const int B = in_sizes[0];                 // 64
    const int total_nodes = in_sizes[1] / 3;   // B*n
    const int n = total_nodes / B;             // 512

    const long long P = (long long)B * n * n;
    float* out      = (float*)d_out;
    float* ei       = out;                // [2P]
    float* maskout  = out + 2 * P;        // [P]
    float* numedges = out + 3 * P;        // [B]
    float* distout  = out + 3 * P + B;    // [P]

    hipLaunchKernelGGL(zero_counts_kernel, dim3((B + 63) / 64), dim3(64), 0, stream,
                       numedges, B);

    const int tpr = n / 4;                              // threads per row (128)
    int rows_per_block = (tpr < 256) ? (256 / tpr) : 1; // 2 for n=512
    const int threads = tpr * rows_per_block;           // 256
    const int nblocks = (B * n) / rows_per_block;       // 16384
    const size_t lds_bytes = (size_t)n * 3 * sizeof(float);

    hipLaunchKernelGGL(cwc_kernel, dim3(nblocks), dim3(threads), lds_bytes, stream,
                       pos, ei, maskout, numedges, distout, n, tpr, rows_per_block);
}

// Round 2
// 262.253 us; speedup vs baseline: 1.3562x; 1.3562x over previous
//
#include <hip/hip_runtime.h>

// ConnectedWithinCutoff: B=64 graphs, n=512 nodes, cutoff=5.0, no self loops.
// d_out (float32, flat): ei[2P] | mask[P] | num_edges[B] | dist[P], P=B*n*n.
// Pure write-streaming problem: 268 MB out -> ~41 us floor at 6.6 TB/s
// (measured fill BW on this chip). Strategy: long dense store streams.
//   - 2048 blocks (8/CU resident, 32 waves/CU), each does 16 rows of a graph.
//   - thread's 4-node j-window is iteration-invariant: LDS-read once, reuse x8.
//   - ei written as 16 fully-dense wave-contiguous float4 pattern stores
//     (gi wave-uniform, gj=2*tid) -- fixes the 50%-density 32B-stride stores.
//   - one count atomic per block (32 per graph address).

__global__ void zero_counts_kernel(float* __restrict__ ne, int B) {
    int t = blockIdx.x * blockDim.x + threadIdx.x;
    if (t < B) ne[t] = 0.0f;
}

__global__ __launch_bounds__(256) void cwc_kernel(
    const float* __restrict__ pos,
    float* __restrict__ ei,
    float* __restrict__ maskout,
    float* __restrict__ numedges,
    float* __restrict__ distout,
    int n)
{
    extern __shared__ float spos[];          // n*3 floats (6 KB for n=512)
    const int ROWS = 16;                     // rows per block
    const int bpg  = n / ROWS;               // blocks per graph (32)
    const int b    = blockIdx.x / bpg;
    const int r0   = (blockIdx.x - b * bpg) * ROWS;
    const int nf   = n * 3;

    // coalesced stage of graph b's positions (L2-hot after first block)
    const float* gp = pos + (long long)b * nf;
    for (int idx = threadIdx.x; idx < nf; idx += blockDim.x)
        spos[idx] = gp[idx];
    __syncthreads();

    const int tid  = threadIdx.x;
    const int tpr  = n / 4;                  // threads per row (128)
    const int half = tid / tpr;              // 0/1: which of 2 rows per iter
    const int jj0  = (tid - half * tpr) * 4; // fixed 4-node j-window

    // load j-window ONCE (12 contiguous floats, 3x ds_read_b128), reuse x8
    float4 q0 = *(const float4*)(spos + 3 * jj0);
    float4 q1 = *(const float4*)(spos + 3 * jj0 + 4);
    float4 q2 = *(const float4*)(spos + 3 * jj0 + 8);
    const float qx[4] = {q0.x, q0.w, q1.z, q2.y};
    const float qy[4] = {q0.y, q1.x, q1.w, q2.z};
    const float qz[4] = {q0.z, q1.y, q2.x, q2.w};

    const int gb = b * n;
    const long long pairbase = (long long)(gb + r0) * n;

    int cnt = 0;
#pragma unroll
    for (int k = 0; k < 8; ++k) {
        const int i = r0 + 2 * k + half;     // row (wave-uniform)
        const float px = spos[3 * i], py = spos[3 * i + 1], pz = spos[3 * i + 2];
        float d[4], m[4];
#pragma unroll
        for (int jj = 0; jj < 4; ++jj) {
            float dx = px - qx[jj];
            float dy = py - qy[jj];
            float dz = pz - qz[jj];
            float dd = sqrtf(fmaf(dx, dx, fmaf(dy, dy, dz * dz)));
            d[jj] = dd;
            bool keep = (dd <= 5.0f) && ((jj0 + jj) != i);
            m[jj] = keep ? 1.0f : 0.0f;
            cnt += keep ? 1 : 0;
        }
        const long long o = pairbase + (long long)(2 * k + half) * n + jj0;
        *(float4*)(distout + o) = float4{d[0], d[1], d[2], d[3]};
        *(float4*)(maskout + o) = float4{m[0], m[1], m[2], m[3]};
    }

    // ei: 16 fully-dense pattern stores. float4s per row = n/2 = blockDim (256).
    // float4 index f = k2*256 + tid  ->  row = r0+k2 (uniform), j = 2*tid.
    float4* eib = (float4*)(ei + 2 * pairbase);
    const float gj0 = (float)(gb + 2 * tid);
#pragma unroll
    for (int k2 = 0; k2 < ROWS; ++k2) {
        const float gif = (float)(gb + r0 + k2);
        eib[k2 * 256 + tid] = float4{gif, gj0, gif, gj0 + 1.0f};
    }

    // block count reduction -> one atomic per block
#pragma unroll
    for (int off = 32; off > 0; off >>= 1)
        cnt += __shfl_down(cnt, off, 64);
    __shared__ int wsum[4];
    const int wave = tid >> 6;
    if ((tid & 63) == 0) wsum[wave] = cnt;
    __syncthreads();
    if (tid == 0) {
        int s = wsum[0] + wsum[1] + wsum[2] + wsum[3];
        atomicAdd(numedges + b, (float)s);
    }
}

extern "C" void kernel_launch(void* const* d_in, const int* in_sizes, int n_in,
                              void* d_out, int out_size, void* d_ws, size_t ws_size,
                              hipStream_t stream) {
    const float* pos = (const float*)d_in[1];  // [B*n, 3] float32
    const int B = in_sizes[0];                 // 64
    const int total_nodes = in_sizes[1] / 3;   // B*n
    const int n = total_nodes / B;             // 512

    const long long P = (long long)B * n * n;
    float* out      = (float*)d_out;
    float* ei       = out;                // [2P]
    float* maskout  = out + 2 * P;        // [P]
    float* numedges = out + 3 * P;        // [B]
    float* distout  = out + 3 * P + B;    // [P]

    hipLaunchKernelGGL(zero_counts_kernel, dim3((B + 63) / 64), dim3(64), 0, stream,
                       numedges, B);

    const int ROWS = 16;
    const int nblocks = B * (n / ROWS);        // 2048
    const size_t lds_bytes = (size_t)n * 3 * sizeof(float);

    hipLaunchKernelGGL(cwc_kernel, dim3(nblocks), dim3(256), lds_bytes, stream,
                       pos, ei, maskout, numedges, distout, n);
}